// Round 2
// baseline (1460.447 us; speedup 1.0000x reference)
//
#include <hip/hip_runtime.h>
#include <math.h>

#define NNODES 100000
#define NEDGES 3200000
#define NFEAT 512
#define HID 16
#define NCLS 40

typedef __attribute__((ext_vector_type(8))) short bf16x8;
typedef __attribute__((ext_vector_type(4))) float f32x4;

// fp32 -> bf16 (RNE) as raw bits
static __device__ __forceinline__ short f2bf(float f) {
    unsigned u = __builtin_bit_cast(unsigned, f);
    unsigned r = (u + 0x7FFFu + ((u >> 16) & 1u)) >> 16;
    return (short)(r & 0xFFFFu);
}

// in-degree (dst side) via int atomics
__global__ void k_deg(const int* __restrict__ dst, int* __restrict__ degI) {
    int e = blockIdx.x * blockDim.x + threadIdx.x;
    if (e < NEDGES) atomicAdd(&degI[dst[e]], 1);
}

// dinv = rsqrt(deg + 1)  (self-loop), written in place over the int degree buffer
__global__ void k_dinv(int* __restrict__ p) {
    int i = blockIdx.x * blockDim.x + threadIdx.x;
    if (i < NNODES) {
        float d = (float)(p[i] + 1);
        float r = rsqrtf(d);
        p[i] = __builtin_bit_cast(int, r);
    }
}

// H1 = x @ W1 (100000x512 @ 512x16), scaled by dinv[row]; writes Hs and AGG (=self-loop init)
// One wave per 16-row tile. W1 held entirely as bf16 B-fragments in registers (64 VGPR).
__global__ __launch_bounds__(256) void k_gemm1(
        const float* __restrict__ x, const float* __restrict__ W1,
        const float* __restrict__ dinv, float* __restrict__ Hs,
        float* __restrict__ AGG) {
    const int lane = threadIdx.x & 63;
    const int wid = blockIdx.x * 4 + (threadIdx.x >> 6);
    const int col = lane & 15;   // A-row / B-col / C-col role
    const int kq = lane >> 4;    // k-quarter

    if (wid >= NNODES / 16) return;

    // B fragments: lane holds W1[s*32 + kq*8 + i][col], i=0..7, for s=0..15
    bf16x8 bfrag[16];
#pragma unroll
    for (int s = 0; s < 16; ++s) {
#pragma unroll
        for (int i = 0; i < 8; ++i) {
            int k = s * 32 + kq * 8 + i;
            bfrag[s][i] = f2bf(W1[k * HID + col]);
        }
    }

    const int row0 = wid * 16;  // NNODES = 6250*16 exactly, no tail
    const float* xr = x + (size_t)(row0 + col) * NFEAT + kq * 8;
    f32x4 acc = {0.f, 0.f, 0.f, 0.f};
#pragma unroll
    for (int s = 0; s < 16; ++s) {
        f32x4 xa = *(const f32x4*)(xr + s * 32);
        f32x4 xb = *(const f32x4*)(xr + s * 32 + 4);
        bf16x8 a;
        a[0] = f2bf(xa[0]); a[1] = f2bf(xa[1]); a[2] = f2bf(xa[2]); a[3] = f2bf(xa[3]);
        a[4] = f2bf(xb[0]); a[5] = f2bf(xb[1]); a[6] = f2bf(xb[2]); a[7] = f2bf(xb[3]);
        acc = __builtin_amdgcn_mfma_f32_16x16x32_bf16(a, bfrag[s], acc, 0, 0, 0);
    }
    // C/D layout: col = lane&15, row = (lane>>4)*4 + i  [m89 verified]
    const int crow = (lane >> 4) * 4;
#pragma unroll
    for (int i = 0; i < 4; ++i) {
        int r = row0 + crow + i;
        float v = acc[i] * dinv[r];
        Hs[r * HID + col] = v;
        AGG[r * HID + col] = v;
    }
}

// AGG[dst] += H[src], 16 floats per edge; 4 lanes per edge, float4 gather + 4 scalar atomics
__global__ void k_agg(const int* __restrict__ es, const int* __restrict__ ed,
                      const float* __restrict__ H, float* AGG) {
    unsigned t = blockIdx.x * blockDim.x + threadIdx.x;
    if (t >= (unsigned)NEDGES * 4u) return;
    int e = (int)(t >> 2), q = (int)(t & 3);
    int s = es[e], d = ed[e];
    f32x4 v = *(const f32x4*)(H + s * HID + q * 4);
    float* o = AGG + d * HID + q * 4;
    atomicAdd(o + 0, v[0]); atomicAdd(o + 1, v[1]);
    atomicAdd(o + 2, v[2]); atomicAdd(o + 3, v[3]);
}

// out1 = relu(dinv*AGG + b1); G = dinv*out1; write G into both HsG (gather src) and AGG (self-loop init)
__global__ void k_relu(const float* __restrict__ b1, const float* __restrict__ dinv,
                       float* __restrict__ HsG, float* __restrict__ AGG) {
    int t = blockIdx.x * blockDim.x + threadIdx.x;
    if (t >= NNODES * 4) return;
    int n = t >> 2, q = t & 3;
    float di = dinv[n];
    f32x4 a = *(const f32x4*)(AGG + n * HID + q * 4);
    f32x4 bv = ((const f32x4*)b1)[q];
    f32x4 g;
#pragma unroll
    for (int i = 0; i < 4; ++i) {
        float o = fmaf(di, a[i], bv[i]);
        o = fmaxf(o, 0.f);
        g[i] = di * o;
    }
    *(f32x4*)(HsG + n * HID + q * 4) = g;
    *(f32x4*)(AGG + n * HID + q * 4) = g;
}

// pre2 = dinv*AGG2; logits = pre2 @ W2 + b2; out = log_softmax(logits)
__global__ __launch_bounds__(256) void k_final(
        const float* __restrict__ AGG, const float* __restrict__ dinv,
        const float* __restrict__ W2, const float* __restrict__ b2,
        float* __restrict__ out) {
    __shared__ float w2s[HID * NCLS];
    __shared__ float b2s[NCLS];
    for (int i = threadIdx.x; i < HID * NCLS; i += blockDim.x) w2s[i] = W2[i];
    if (threadIdx.x < NCLS) b2s[threadIdx.x] = b2[threadIdx.x];
    __syncthreads();
    int n = blockIdx.x * blockDim.x + threadIdx.x;
    if (n >= NNODES) return;
    float di = dinv[n];
    float h[HID];
#pragma unroll
    for (int q = 0; q < 4; ++q) {
        f32x4 v = *(const f32x4*)(AGG + n * HID + q * 4);
#pragma unroll
        for (int i = 0; i < 4; ++i) h[q * 4 + i] = di * v[i];
    }
    float m = -1e30f;
    float l[NCLS];
#pragma unroll
    for (int j = 0; j < NCLS; ++j) {
        float sacc = b2s[j];
#pragma unroll
        for (int k = 0; k < HID; ++k) sacc = fmaf(h[k], w2s[k * NCLS + j], sacc);
        l[j] = sacc;
        m = fmaxf(m, sacc);
    }
    float ssum = 0.f;
#pragma unroll
    for (int j = 0; j < NCLS; ++j) ssum += expf(l[j] - m);
    float lg = m + logf(ssum);
    f32x4* orow = (f32x4*)(out + (size_t)n * NCLS);
#pragma unroll
    for (int j4 = 0; j4 < NCLS / 4; ++j4) {
        f32x4 o;
        o[0] = l[j4 * 4 + 0] - lg; o[1] = l[j4 * 4 + 1] - lg;
        o[2] = l[j4 * 4 + 2] - lg; o[3] = l[j4 * 4 + 3] - lg;
        orow[j4] = o;
    }
}

extern "C" void kernel_launch(void* const* d_in, const int* in_sizes, int n_in,
                              void* d_out, int out_size, void* d_ws, size_t ws_size,
                              hipStream_t stream) {
    const float* x  = (const float*)d_in[0];
    const float* W1 = (const float*)d_in[1];
    const float* b1 = (const float*)d_in[2];
    const float* W2 = (const float*)d_in[3];
    const float* b2 = (const float*)d_in[4];
    const int* ei   = (const int*)d_in[5];   // int64 in reference -> int32 from harness
    const int* esrc = ei;
    const int* edst = ei + NEDGES;

    char* ws = (char*)d_ws;
    int* degp   = (int*)ws;                  // 400 KB, becomes dinv (float) in place
    float* dinv = (float*)ws;
    float* HsG  = (float*)(ws + (1 << 20));  // 6.4 MB: dinv-scaled features (gather source)
    float* AGG  = (float*)(ws + (8 << 20));  // 6.4 MB: aggregation accumulator
    float* outp = (float*)d_out;

    hipMemsetAsync(degp, 0, NNODES * sizeof(int), stream);
    k_deg<<<(NEDGES + 255) / 256, 256, 0, stream>>>(edst, degp);
    k_dinv<<<(NNODES + 255) / 256, 256, 0, stream>>>(degp);
    k_gemm1<<<(NNODES / 16 + 3) / 4, 256, 0, stream>>>(x, W1, dinv, HsG, AGG);
    k_agg<<<(NEDGES * 4 + 255) / 256, 256, 0, stream>>>(esrc, edst, HsG, AGG);
    k_relu<<<(NNODES * 4 + 255) / 256, 256, 0, stream>>>(b1, dinv, HsG, AGG);
    k_agg<<<(NEDGES * 4 + 255) / 256, 256, 0, stream>>>(esrc, edst, HsG, AGG);
    k_final<<<(NNODES + 255) / 256, 256, 0, stream>>>(AGG, dinv, W2, b2, outp);
}

// Round 4
// 536.769 us; speedup vs baseline: 2.7208x; 2.7208x over previous
//
#include <hip/hip_runtime.h>
#include <math.h>

#define NNODES 100000
#define NEDGES 3200000
#define NFEAT 512
#define HID 16
#define NCLS 40

typedef __attribute__((ext_vector_type(8))) short bf16x8;
typedef __attribute__((ext_vector_type(4))) float f32x4;

// fp32 -> bf16 (RNE) as raw bits
static __device__ __forceinline__ short f2bf(float f) {
    unsigned u = __builtin_bit_cast(unsigned, f);
    unsigned r = (u + 0x7FFFu + ((u >> 16) & 1u)) >> 16;
    return (short)(r & 0xFFFFu);
}

// ---------- degree / norm ----------
__global__ void k_deg(const int* __restrict__ dst, int* __restrict__ degI) {
    int e = blockIdx.x * blockDim.x + threadIdx.x;
    if (e < NEDGES) atomicAdd(&degI[dst[e]], 1);
}

// dinv = rsqrt(deg + 1) (self-loop) -- separate output, deg kept for the scan
__global__ void k_dinv(const int* __restrict__ deg, float* __restrict__ dinv) {
    int i = blockIdx.x * blockDim.x + threadIdx.x;
    if (i < NNODES) dinv[i] = rsqrtf((float)(deg[i] + 1));
}

// ---------- CSR build: exclusive scan of deg -> row_start, then cursor-scatter ----------
// chunk = 1024 elements per block (256 thr x 4)
__global__ __launch_bounds__(256) void k_scan1(const int* __restrict__ deg,
                                               int* __restrict__ rs, int* __restrict__ csum) {
    __shared__ int lds[256];
    int t = threadIdx.x;
    int base = blockIdx.x * 1024 + t * 4;
    int a0 = (base + 0 < NNODES) ? deg[base + 0] : 0;
    int a1 = (base + 1 < NNODES) ? deg[base + 1] : 0;
    int a2 = (base + 2 < NNODES) ? deg[base + 2] : 0;
    int a3 = (base + 3 < NNODES) ? deg[base + 3] : 0;
    int s = a0 + a1 + a2 + a3;
    lds[t] = s;
    __syncthreads();
    for (int off = 1; off < 256; off <<= 1) {
        int x = (t >= off) ? lds[t - off] : 0;
        __syncthreads();
        lds[t] += x;
        __syncthreads();
    }
    int excl = (t > 0) ? lds[t - 1] : 0;
    if (base + 0 < NNODES) rs[base + 0] = excl;
    if (base + 1 < NNODES) rs[base + 1] = excl + a0;
    if (base + 2 < NNODES) rs[base + 2] = excl + a0 + a1;
    if (base + 3 < NNODES) rs[base + 3] = excl + a0 + a1 + a2;
    if (t == 255) csum[blockIdx.x] = lds[255];
}

#define NCHUNK 98  // ceil(100000/1024)
__global__ __launch_bounds__(128) void k_scan2(int* __restrict__ csum) {
    __shared__ int lds[128];
    int t = threadIdx.x;
    lds[t] = (t < NCHUNK) ? csum[t] : 0;
    __syncthreads();
    for (int off = 1; off < 128; off <<= 1) {
        int x = (t >= off) ? lds[t - off] : 0;
        __syncthreads();
        lds[t] += x;
        __syncthreads();
    }
    if (t < NCHUNK) csum[t] = (t > 0) ? lds[t - 1] : 0;
}

__global__ void k_scan3(int* __restrict__ rs, const int* __restrict__ csum,
                        int* __restrict__ cursor) {
    int i = blockIdx.x * blockDim.x + threadIdx.x;
    if (i < NNODES) {
        int v = rs[i] + csum[i >> 10];
        rs[i] = v;
        cursor[i] = v;
    }
    if (i == NNODES) rs[NNODES] = NEDGES;
}

__global__ void k_scatter(const int* __restrict__ es, const int* __restrict__ ed,
                          int* __restrict__ cursor, int* __restrict__ csr) {
    int e = blockIdx.x * blockDim.x + threadIdx.x;
    if (e < NEDGES) {
        int pos = atomicAdd(&cursor[ed[e]], 1);
        csr[pos] = es[e];
    }
}

// ---------- layer-1 GEMM: Hs = dinv * (x @ W1) ----------
__global__ __launch_bounds__(256) void k_gemm1(
        const float* __restrict__ x, const float* __restrict__ W1,
        const float* __restrict__ dinv, float* __restrict__ Hs) {
    const int lane = threadIdx.x & 63;
    const int wid = blockIdx.x * 4 + (threadIdx.x >> 6);
    const int col = lane & 15;
    const int kq = lane >> 4;
    if (wid >= NNODES / 16) return;

    bf16x8 bfrag[16];
#pragma unroll
    for (int s = 0; s < 16; ++s) {
#pragma unroll
        for (int i = 0; i < 8; ++i) {
            int k = s * 32 + kq * 8 + i;
            bfrag[s][i] = f2bf(W1[k * HID + col]);
        }
    }
    const int row0 = wid * 16;
    const float* xr = x + (size_t)(row0 + col) * NFEAT + kq * 8;
    f32x4 acc = {0.f, 0.f, 0.f, 0.f};
#pragma unroll
    for (int s = 0; s < 16; ++s) {
        f32x4 xa = *(const f32x4*)(xr + s * 32);
        f32x4 xb = *(const f32x4*)(xr + s * 32 + 4);
        bf16x8 a;
        a[0] = f2bf(xa[0]); a[1] = f2bf(xa[1]); a[2] = f2bf(xa[2]); a[3] = f2bf(xa[3]);
        a[4] = f2bf(xb[0]); a[5] = f2bf(xb[1]); a[6] = f2bf(xb[2]); a[7] = f2bf(xb[3]);
        acc = __builtin_amdgcn_mfma_f32_16x16x32_bf16(a, bfrag[s], acc, 0, 0, 0);
    }
    const int crow = (lane >> 4) * 4;
#pragma unroll
    for (int i = 0; i < 4; ++i) {
        int r = row0 + crow + i;
        Hs[r * HID + col] = acc[i] * dinv[r];
    }
}

// ---------- CSR gather: out[n] = f( H[n] + sum_{s in N(n)} H[s] ) ----------
// 16 lanes per node (4 neighbor-slots x 4 channel-quads), 4 nodes per wave,
// 16 nodes per 256-thread block.
// FUSE_RELU: out = dinv * relu(dinv * acc + b1)   else: out = acc
template <int FUSE_RELU>
__global__ __launch_bounds__(256) void k_gather(
        const float* __restrict__ H, const int* __restrict__ rs,
        const int* __restrict__ csr, const float* __restrict__ dinv,
        const float* __restrict__ b1, float* __restrict__ out) {
    const int lane = threadIdx.x & 63;
    const int wid = blockIdx.x * 4 + (threadIdx.x >> 6);
    const int n = wid * 4 + (lane >> 4);
    if (n >= NNODES) return;
    const int l = lane & 15;
    const int q = l & 3;   // channel quad
    const int j = l >> 2;  // neighbor slot

    const int beg = rs[n], end = rs[n + 1];
    f32x4 acc = {0.f, 0.f, 0.f, 0.f};
    if (j == 0) acc = *(const f32x4*)(H + (size_t)n * HID + q * 4);  // self loop
    for (int p = beg + j; p < end; p += 4) {
        int s = csr[p];
        acc += *(const f32x4*)(H + (size_t)s * HID + q * 4);
    }
    // reduce over neighbor slots (lane bits 2,3)
#pragma unroll
    for (int m = 4; m <= 8; m <<= 1) {
#pragma unroll
        for (int i = 0; i < 4; ++i) acc[i] += __shfl_xor(acc[i], m, 64);
    }
    if (j == 0) {
        if (FUSE_RELU) {
            float di = dinv[n];
            f32x4 bq = ((const f32x4*)b1)[q];
            f32x4 g;
#pragma unroll
            for (int i = 0; i < 4; ++i) {
                float o = fmaf(di, acc[i], bq[i]);
                o = fmaxf(o, 0.f);
                g[i] = di * o;
            }
            *(f32x4*)(out + (size_t)n * HID + q * 4) = g;
        } else {
            *(f32x4*)(out + (size_t)n * HID + q * 4) = acc;
        }
    }
}

// ---------- final: logits = (dinv*AGG2) @ W2 + b2 ; out = log_softmax ----------
__global__ __launch_bounds__(256) void k_final(
        const float* __restrict__ AGG, const float* __restrict__ dinv,
        const float* __restrict__ W2, const float* __restrict__ b2,
        float* __restrict__ out) {
    __shared__ float w2s[HID * NCLS];
    __shared__ float b2s[NCLS];
    for (int i = threadIdx.x; i < HID * NCLS; i += blockDim.x) w2s[i] = W2[i];
    if (threadIdx.x < NCLS) b2s[threadIdx.x] = b2[threadIdx.x];
    __syncthreads();
    int n = blockIdx.x * blockDim.x + threadIdx.x;
    if (n >= NNODES) return;
    float di = dinv[n];
    float h[HID];
#pragma unroll
    for (int qq = 0; qq < 4; ++qq) {
        f32x4 v = *(const f32x4*)(AGG + (size_t)n * HID + qq * 4);
#pragma unroll
        for (int i = 0; i < 4; ++i) h[qq * 4 + i] = di * v[i];
    }
    float m = -1e30f;
    float l[NCLS];
#pragma unroll
    for (int j = 0; j < NCLS; ++j) {
        float sacc = b2s[j];
#pragma unroll
        for (int k = 0; k < HID; ++k) sacc = fmaf(h[k], w2s[k * NCLS + j], sacc);
        l[j] = sacc;
        m = fmaxf(m, sacc);
    }
    float ssum = 0.f;
#pragma unroll
    for (int j = 0; j < NCLS; ++j) ssum += expf(l[j] - m);
    float lg = m + logf(ssum);
    f32x4* orow = (f32x4*)(out + (size_t)n * NCLS);
#pragma unroll
    for (int j4 = 0; j4 < NCLS / 4; ++j4) {
        f32x4 o;
        o[0] = l[j4 * 4 + 0] - lg; o[1] = l[j4 * 4 + 1] - lg;
        o[2] = l[j4 * 4 + 2] - lg; o[3] = l[j4 * 4 + 3] - lg;
        orow[j4] = o;
    }
}

extern "C" void kernel_launch(void* const* d_in, const int* in_sizes, int n_in,
                              void* d_out, int out_size, void* d_ws, size_t ws_size,
                              hipStream_t stream) {
    const float* x  = (const float*)d_in[0];
    const float* W1 = (const float*)d_in[1];
    const float* b1 = (const float*)d_in[2];
    const float* W2 = (const float*)d_in[3];
    const float* b2 = (const float*)d_in[4];
    const int* ei   = (const int*)d_in[5];   // int64 in reference -> int32 from harness
    const int* esrc = ei;
    const int* edst = ei + NEDGES;

    char* ws = (char*)d_ws;
    int*   deg    = (int*)(ws + 0);              // 400 KB (also cursor after scan)
    float* dinv   = (float*)(ws + (1 << 19));    // 400 KB
    int*   rs     = (int*)(ws + (1 << 20));      // 400 KB + 4 (row_start[N+1])
    int*   csum   = (int*)(ws + (3 << 19));      // 512 B
    int*   csr    = (int*)(ws + (2 << 20));      // 12.8 MB
    float* Hs     = (float*)(ws + (15 << 20));   // 6.4 MB (layer-1 features; reused as AGG2)
    float* G      = (float*)(ws + (22 << 20));   // 6.4 MB (layer-2 gather source)
    float* AGG2   = Hs;                          // reuse (Hs dead after gather1)
    float* outp   = (float*)d_out;

    hipMemsetAsync(deg, 0, NNODES * sizeof(int), stream);
    k_deg<<<(NEDGES + 255) / 256, 256, 0, stream>>>(edst, deg);
    k_dinv<<<(NNODES + 255) / 256, 256, 0, stream>>>(deg, dinv);
    k_scan1<<<NCHUNK, 256, 0, stream>>>(deg, rs, csum);
    k_scan2<<<1, 128, 0, stream>>>(csum);
    k_scan3<<<(NNODES + 256) / 256, 256, 0, stream>>>(rs, csum, deg /*cursor*/);
    k_scatter<<<(NEDGES + 255) / 256, 256, 0, stream>>>(esrc, edst, deg /*cursor*/, csr);
    k_gemm1<<<(NNODES / 16 + 3) / 4, 256, 0, stream>>>(x, W1, dinv, Hs);
    // 16 nodes per block -> ceil(100000/16) = 6250 blocks
    k_gather<1><<<(NNODES + 15) / 16, 256, 0, stream>>>(Hs, rs, csr, dinv, b1, G);
    k_gather<0><<<(NNODES + 15) / 16, 256, 0, stream>>>(G, rs, csr, dinv, b1, AGG2);
    k_final<<<(NNODES + 255) / 256, 256, 0, stream>>>(AGG2, dinv, W2, b2, outp);
}